// Round 12
// baseline (442.921 us; speedup 1.0000x reference)
//
#include <hip/hip_runtime.h>

// entmax-1.5 attention, round 12: r11 structure with Newton restored to 6
// iterations (r11's 5-iter cut caused absmax 0.086 > 0.083 threshold).
// Persistent blocks (grid 256, 4 chunks/block, same head) + vr0/vr1 preloaded
// under Newton + vr2/vr3 under Phase C. B*H=16, S=2048, D=128, fp32 I/O.
//
// Prepass (r6, proven): K -> K16F sigma-permuted MFMA A-frag layout;
//   V -> V16T2 PV A-frag layout. QK^T C-regs are directly PV B-frags.
// Phase A: swapped QK^T, ds-outer (8 independent MFMAs per step), kA/kB ring.
// Phase R: z (f16, no max-sub) -> zbuf rows (swizzled), 1 barrier.
// Phase B: wave-local row max + 6 Newton iters, 4-way split f/g chains.
// Phase C/D: p=(z-tau)^2 in sigma-layout regs; PV all-register, V ring depth 4.
// Phase E: 8-region partial write (aliases zbuf) + coop sum.

constexpr int S = 2048;
constexpr int D = 128;
constexpr int NH = 16;

typedef _Float16 f16x8 __attribute__((ext_vector_type(8)));
typedef _Float16 v2h   __attribute__((ext_vector_type(2)));
typedef __fp16   fp16x2 __attribute__((ext_vector_type(2)));
typedef float f32x4  __attribute__((ext_vector_type(4)));
typedef float f32x16 __attribute__((ext_vector_type(16)));

union H8 { f16x8 v; fp16x2 h[4]; };
union PK { fp16x2 a; v2h b; };
union Z  { f16x8 f8[16]; v2h v2[64]; };

__device__ __forceinline__ f16x8 cvt8(float4 a, float4 b) {
  H8 r;
  r.h[0] = __builtin_amdgcn_cvt_pkrtz(a.x, a.y);
  r.h[1] = __builtin_amdgcn_cvt_pkrtz(a.z, a.w);
  r.h[2] = __builtin_amdgcn_cvt_pkrtz(b.x, b.y);
  r.h[3] = __builtin_amdgcn_cvt_pkrtz(b.z, b.w);
  return r.v;
}

// ---- prepass: K16F (sigma-permuted A-frag layout) + V16T2 (PV A-frag) ----
__global__ __launch_bounds__(256)
void prepass(const float* __restrict__ K, const float* __restrict__ V,
             _Float16* __restrict__ K16F, _Float16* __restrict__ V16T2) {
  __shared__ float tile[32][128];
  const int tid  = threadIdx.x;
  const int tb   = blockIdx.x;     // 32-row k-tile, 0..63
  const int head = blockIdx.y;
  const size_t hb = (size_t)head * S * D;
  const float* Kt = K + hb + (size_t)tb * 32 * D;
  const float* Vt = V + hb + (size_t)tb * 32 * D;

#pragma unroll
  for (int it = 0; it < 4; ++it) {
    int idx = it * 256 + tid;
    int row = idx >> 5, c = idx & 31;
    *(float4*)&tile[row][c * 4] = *(const float4*)(Kt + (size_t)row * D + c * 4);
  }
  __syncthreads();
#pragma unroll
  for (int it = 0; it < 2; ++it) {
    int s = it * 256 + tid;
    int r = s & 31, g = s >> 5;
    int ds = g >> 1, hh = g & 1;
    int sr = (r & 19) | ((r & 4) << 1) | ((r & 8) >> 1);   // swap bits 2,3
    const float* src = &tile[sr][ds * 16 + 8 * hh];
    f16x8 o;
#pragma unroll
    for (int i = 0; i < 8; ++i) o[i] = (_Float16)src[i];
    *(f16x8*)(K16F + ((size_t)(head * 64 + tb) * 16 + g) * 256 + r * 8) = o;
  }
  __syncthreads();
#pragma unroll
  for (int it = 0; it < 4; ++it) {
    int idx = it * 256 + tid;
    int row = idx >> 5, c = idx & 31;
    *(float4*)&tile[row][c * 4] = *(const float4*)(Vt + (size_t)row * D + c * 4);
  }
  __syncthreads();
#pragma unroll
  for (int it = 0; it < 2; ++it) {
    int s = it * 256 + tid;
    int dd = s & 31, g = s >> 5;
    int hh = g & 1, dt = (g >> 1) & 3, kl = g >> 3;
    f16x8 o;
#pragma unroll
    for (int i = 0; i < 8; ++i) o[i] = (_Float16)tile[kl * 16 + 8 * hh + i][dt * 32 + dd];
    *(f16x8*)(V16T2 + (((size_t)(head * 128 + tb * 2 + kl) * 4 + dt) * 2 + hh) * 256 + dd * 8) = o;
  }
}

__global__ __launch_bounds__(512, 2)
void entmax_attn(const float* __restrict__ Q, const _Float16* __restrict__ K16F,
                 const _Float16* __restrict__ V16T2, float* __restrict__ O) {
  __shared__ __align__(16) char zbuf[131072];   // 32q x 4096B z rows; alias oreg
  __shared__ float taubuf[32];

  const int tid  = threadIdx.x;
  const int lane = tid & 63;
  const int wid  = tid >> 6;
  const int l31  = lane & 31;
  const int h    = lane >> 5;

  // persistent: grid 256 = 8 XCD x 2 heads x 16 blocks; 4 q-chunks per block
  const int bi   = blockIdx.x;
  const int j    = bi >> 3;
  const int head = (bi & 7) * 2 + (j >> 4);
  const int cb   = (j & 15) * 4;

  const size_t hb = (size_t)head * S * D;
  const float* Qh = Q + hb;
  float* Oh = O + hb;

  const _Float16* kfp = K16F + ((size_t)(head * 64 + wid * 8)) * 4096 + lane * 8;
  const _Float16* vfp = V16T2 + ((size_t)(head * 128 + wid * 16)) * 2048 + lane * 8;

  const float hs = 0.04419417382415922f;  // 0.5 / sqrt(128)
  const v2h zero2 = {(_Float16)0.f, (_Float16)0.f};
  const v2h one2  = {(_Float16)1.f, (_Float16)1.f};

  for (int c4 = 0; c4 < 4; ++c4) {
    const int qb = (cb + c4) * 32;

    // ---- Q fragments (hs folded): B[d][q], q=l31, d = ds*16 + 8h + i ----
    f16x8 qf[8];
    {
      const float* qr = Qh + (size_t)(qb + l31) * D + 8 * h;
#pragma unroll
      for (int ds = 0; ds < 8; ++ds) {
        float4 a = *(const float4*)(qr + ds * 16);
        float4 b = *(const float4*)(qr + ds * 16 + 4);
        a.x *= hs; a.y *= hs; a.z *= hs; a.w *= hs;
        b.x *= hs; b.y *= hs; b.z *= hs; b.w *= hs;
        qf[ds] = cvt8(a, b);
      }
    }

    // ---- Phase A: QK^T, ds-outer => 8 independent MFMAs per step ----
    f32x16 acc[8];
#pragma unroll
    for (int t = 0; t < 8; ++t)
#pragma unroll
      for (int e = 0; e < 16; ++e) acc[t][e] = 0.f;

    {
      f16x8 kA[8], kB[8];
#pragma unroll
      for (int t = 0; t < 8; ++t) kA[t] = *(const f16x8*)(kfp + t * 4096);
#pragma unroll
      for (int t = 0; t < 8; ++t) kB[t] = *(const f16x8*)(kfp + t * 4096 + 512);
#pragma unroll
      for (int dd = 0; dd < 4; ++dd) {
#pragma unroll
        for (int t = 0; t < 8; ++t) {
          acc[t] = __builtin_amdgcn_mfma_f32_32x32x16_f16(kA[t], qf[2 * dd], acc[t], 0, 0, 0);
          if (dd < 3) kA[t] = *(const f16x8*)(kfp + t * 4096 + (2 * dd + 2) * 512);
        }
#pragma unroll
        for (int t = 0; t < 8; ++t) {
          acc[t] = __builtin_amdgcn_mfma_f32_32x32x16_f16(kB[t], qf[2 * dd + 1], acc[t], 0, 0, 0);
          if (dd < 3) kB[t] = *(const f16x8*)(kfp + t * 4096 + (2 * dd + 3) * 512);
        }
      }
    }

    // ---- z = acc (f16, no max-sub; entmax is shift-invariant) ----
    Z z;
#pragma unroll
    for (int t = 0; t < 8; ++t)
#pragma unroll
      for (int j2 = 0; j2 < 8; ++j2) {
        PK pk;
        pk.a = __builtin_amdgcn_cvt_pkrtz(acc[t][2 * j2], acc[t][2 * j2 + 1]);
        z.v2[t * 8 + j2] = pk.b;
      }

    // ---- vr0+vr1 prefetch (32 VGPR; complete under Newton) ----
    f16x8 vr0[4], vr1[4];
#pragma unroll
    for (int dt = 0; dt < 4; ++dt) vr0[dt] = *(const f16x8*)(vfp + dt * 512);
#pragma unroll
    for (int dt = 0; dt < 4; ++dt) vr1[dt] = *(const f16x8*)(vfp + 1 * 2048 + dt * 512);

    // ---- Phase R: redistribute z -> zbuf (row q, swizzled) ----
    {
      const int sw = (l31 & 7) << 4;
#pragma unroll
      for (int kt = 0; kt < 16; ++kt) {
        const int by = l31 * 4096 + ((wid * 512 + kt * 32 + 16 * h) ^ sw);
        *(f16x8*)(zbuf + by) = z.f8[kt];
      }
    }
    __syncthreads();   // barrier 1

    // ---- Phase B: wave-local row max + 6 Newton iters (4-way split) ----
    {
      const int r = lane >> 4, c = lane & 15;
      const int q = wid * 4 + r;
      const int swq = (q & 7) << 4;
      Z zr;
#pragma unroll
      for (int j2 = 0; j2 < 16; ++j2)
        zr.f8[j2] = *(const f16x8*)(zbuf + q * 4096 + ((c * 256 + j2 * 16) ^ swq));

      v2h mv = zr.v2[0];
#pragma unroll
      for (int j2 = 1; j2 < 64; ++j2) mv = __builtin_elementwise_max(mv, zr.v2[j2]);
      float mx = fmaxf((float)mv[0], (float)mv[1]);
#pragma unroll
      for (int off = 8; off >= 1; off >>= 1) mx = fmaxf(mx, __shfl_xor(mx, off));

      float tau = mx - 1.f;
#pragma unroll
      for (int it = 0; it < 6; ++it) {
        const _Float16 th = (_Float16)tau;
        const v2h tt = {th, th};
        float f0 = 0.f, f1 = 0.f, f2 = 0.f, f3 = 0.f;
        float g0 = 0.f, g1 = 0.f, g2 = 0.f, g3 = 0.f;
#pragma unroll
        for (int j2 = 0; j2 < 64; j2 += 4) {
          v2h d0 = __builtin_elementwise_max(zr.v2[j2 + 0] - tt, zero2);
          v2h d1 = __builtin_elementwise_max(zr.v2[j2 + 1] - tt, zero2);
          v2h d2 = __builtin_elementwise_max(zr.v2[j2 + 2] - tt, zero2);
          v2h d3 = __builtin_elementwise_max(zr.v2[j2 + 3] - tt, zero2);
#if __has_builtin(__builtin_amdgcn_fdot2)
          f0 = __builtin_amdgcn_fdot2(d0, d0, f0, false);
          g0 = __builtin_amdgcn_fdot2(d0, one2, g0, false);
          f1 = __builtin_amdgcn_fdot2(d1, d1, f1, false);
          g1 = __builtin_amdgcn_fdot2(d1, one2, g1, false);
          f2 = __builtin_amdgcn_fdot2(d2, d2, f2, false);
          g2 = __builtin_amdgcn_fdot2(d2, one2, g2, false);
          f3 = __builtin_amdgcn_fdot2(d3, d3, f3, false);
          g3 = __builtin_amdgcn_fdot2(d3, one2, g3, false);
#else
          float e0 = (float)d0[0], e1 = (float)d0[1];
          f0 = fmaf(e0, e0, fmaf(e1, e1, f0)); g0 += e0 + e1;
          e0 = (float)d1[0]; e1 = (float)d1[1];
          f1 = fmaf(e0, e0, fmaf(e1, e1, f1)); g1 += e0 + e1;
          e0 = (float)d2[0]; e1 = (float)d2[1];
          f2 = fmaf(e0, e0, fmaf(e1, e1, f2)); g2 += e0 + e1;
          e0 = (float)d3[0]; e1 = (float)d3[1];
          f3 = fmaf(e0, e0, fmaf(e1, e1, f3)); g3 += e0 + e1;
#endif
        }
        float f = (f0 + f1) + (f2 + f3);
        float g = (g0 + g1) + (g2 + g3);
#pragma unroll
        for (int off = 8; off >= 1; off >>= 1) {
          f += __shfl_xor(f, off);
          g += __shfl_xor(g, off);
        }
        tau += (f - 1.f) / (2.f * fmaxf(g, 1e-20f));
      }
      if (c == 0) taubuf[q] = tau;
    }
    __syncthreads();   // barrier 2 (zbuf reads done -> oreg alias safe)

    // ---- vr2/vr3 prefetch (in flight during Phase C VALU) ----
    f16x8 vr2[4], vr3[4];
#pragma unroll
    for (int dt = 0; dt < 4; ++dt) vr2[dt] = *(const f16x8*)(vfp + 2 * 2048 + dt * 512);
#pragma unroll
    for (int dt = 0; dt < 4; ++dt) vr3[dt] = *(const f16x8*)(vfp + 3 * 2048 + dt * 512);

    // ---- Phase C: p = (z - tau)^2 in place (sigma-layout = PV B-frags) ----
    {
      const _Float16 th = (_Float16)taubuf[l31];
      const v2h tt = {th, th};
#pragma unroll
      for (int j2 = 0; j2 < 64; ++j2) {
        v2h d = __builtin_elementwise_max(z.v2[j2] - tt, zero2);
        z.v2[j2] = d * d;
      }
    }

    // ---- Phase D: O^T partial = V^T P; static depth-4 ring, split oacc ----
    f32x16 oA[4], oB[4];
#pragma unroll
    for (int dt = 0; dt < 4; ++dt)
#pragma unroll
      for (int e = 0; e < 16; ++e) { oA[dt][e] = 0.f; oB[dt][e] = 0.f; }

#pragma unroll
    for (int kq = 0; kq < 4; ++kq) {
#pragma unroll
      for (int dt = 0; dt < 4; ++dt) {
        oA[dt] = __builtin_amdgcn_mfma_f32_32x32x16_f16(vr0[dt], z.f8[4 * kq + 0], oA[dt], 0, 0, 0);
        if (kq < 3) vr0[dt] = *(const f16x8*)(vfp + (4 * kq + 4) * 2048 + dt * 512);
      }
#pragma unroll
      for (int dt = 0; dt < 4; ++dt) {
        oB[dt] = __builtin_amdgcn_mfma_f32_32x32x16_f16(vr1[dt], z.f8[4 * kq + 1], oB[dt], 0, 0, 0);
        if (kq < 3) vr1[dt] = *(const f16x8*)(vfp + (4 * kq + 5) * 2048 + dt * 512);
      }
#pragma unroll
      for (int dt = 0; dt < 4; ++dt) {
        oA[dt] = __builtin_amdgcn_mfma_f32_32x32x16_f16(vr2[dt], z.f8[4 * kq + 2], oA[dt], 0, 0, 0);
        if (kq < 3) vr2[dt] = *(const f16x8*)(vfp + (4 * kq + 6) * 2048 + dt * 512);
      }
#pragma unroll
      for (int dt = 0; dt < 4; ++dt) {
        oB[dt] = __builtin_amdgcn_mfma_f32_32x32x16_f16(vr3[dt], z.f8[4 * kq + 3], oB[dt], 0, 0, 0);
        if (kq < 3) vr3[dt] = *(const f16x8*)(vfp + (4 * kq + 7) * 2048 + dt * 512);
      }
    }

    // ---- Phase E: 8-region partial write (alias zbuf) + coop sum ----
    {
      char* b = zbuf + wid * 16384;
#pragma unroll
      for (int dt = 0; dt < 4; ++dt)
#pragma unroll
        for (int eq = 0; eq < 4; ++eq) {
          int d0 = dt * 32 + 8 * eq + 4 * h;
          int by = l31 * 512 + ((d0 * 4) ^ ((l31 & 7) << 4));
          f32x4 v = {oA[dt][eq * 4 + 0] + oB[dt][eq * 4 + 0],
                     oA[dt][eq * 4 + 1] + oB[dt][eq * 4 + 1],
                     oA[dt][eq * 4 + 2] + oB[dt][eq * 4 + 2],
                     oA[dt][eq * 4 + 3] + oB[dt][eq * 4 + 3]};
          *(f32x4*)(b + by) = v;
        }
    }
    __syncthreads();   // barrier 3
    {
      int q = tid >> 4, dq = tid & 15;
      int by0 = q * 512 + ((dq * 32) ^ ((q & 7) << 4));
      int by1 = q * 512 + ((dq * 32 + 16) ^ ((q & 7) << 4));
      f32x4 s0 = {0.f, 0.f, 0.f, 0.f}, s1 = {0.f, 0.f, 0.f, 0.f};
#pragma unroll
      for (int r = 0; r < 8; ++r) {
        const char* b = zbuf + r * 16384;
        f32x4 v0 = *(const f32x4*)(b + by0);
        f32x4 v1 = *(const f32x4*)(b + by1);
#pragma unroll
        for (int cc = 0; cc < 4; ++cc) { s0[cc] += v0[cc]; s1[cc] += v1[cc]; }
      }
      float* op = Oh + (size_t)(qb + q) * D + dq * 8;
      *(f32x4*)op = s0;
      *(f32x4*)(op + 4) = s1;
    }
    if (c4 < 3) __syncthreads();   // barrier 4: zbuf safe for next chunk
  }
}

extern "C" void kernel_launch(void* const* d_in, const int* in_sizes, int n_in,
                              void* d_out, int out_size, void* d_ws, size_t ws_size,
                              hipStream_t stream) {
  const float* q = (const float*)d_in[0];
  const float* k = (const float*)d_in[1];
  const float* v = (const float*)d_in[2];
  float* out = (float*)d_out;

  const size_t nelem = (size_t)NH * S * D;
  _Float16* k16f  = (_Float16*)d_ws;
  _Float16* v16t2 = k16f + nelem;

  prepass<<<dim3(S / 32, NH), dim3(256), 0, stream>>>(k, v, k16f, v16t2);
  entmax_attn<<<dim3(256), dim3(512), 0, stream>>>(q, k16f, v16t2, out);
}

// Round 13
// 106.118 us; speedup vs baseline: 4.1738x; 4.1738x over previous
//
#include <hip/hip_runtime.h>

// entmax-1.5 attention, round 13: r10 base (grid 1024, NO outer chunk loop --
// r9/r12 showed LLVM pipelines it into a register spill) + two safe tweaks:
//  (1) zbuf combined swizzle b ^ ((((b>>8)^q)&7)<<4): phase-B row reads go
//      from same-bank aliasing to 2-way (free); writes stay 4-way.
//  (2) vr0+vr1 preloaded before Newton; vr2/vr3 right after barrier 2 so
//      Phase C VALU hides their L2 latency.
// B*H=16 heads, S=2048, D=128, fp32 I/O. Block = 512 (8 waves), 32 q. Grid 1024.
//
// Prepass (r6, proven): K -> K16F sigma-permuted MFMA A-frag layout;
//   V -> V16T2 PV A-frag layout. QK^T C-regs are directly PV B-frags.
// Phase A: swapped QK^T, ds-outer (8 independent MFMAs per step), kA/kB ring.
// Phase R: z (f16, no max-sub) -> zbuf rows (combined swizzle), 1 barrier.
// Phase B: wave-local row max + 6 Newton iters, 4-way split f/g chains.
// Phase C/D: p=(z-tau)^2 in sigma-layout regs; PV all-register, V ring depth 4.
// Phase E: 8-region partial write (aliases zbuf) + coop sum.

constexpr int S = 2048;
constexpr int D = 128;
constexpr int NH = 16;

typedef _Float16 f16x8 __attribute__((ext_vector_type(8)));
typedef _Float16 v2h   __attribute__((ext_vector_type(2)));
typedef __fp16   fp16x2 __attribute__((ext_vector_type(2)));
typedef float f32x4  __attribute__((ext_vector_type(4)));
typedef float f32x16 __attribute__((ext_vector_type(16)));

union H8 { f16x8 v; fp16x2 h[4]; };
union PK { fp16x2 a; v2h b; };
union Z  { f16x8 f8[16]; v2h v2[64]; };

__device__ __forceinline__ f16x8 cvt8(float4 a, float4 b) {
  H8 r;
  r.h[0] = __builtin_amdgcn_cvt_pkrtz(a.x, a.y);
  r.h[1] = __builtin_amdgcn_cvt_pkrtz(a.z, a.w);
  r.h[2] = __builtin_amdgcn_cvt_pkrtz(b.x, b.y);
  r.h[3] = __builtin_amdgcn_cvt_pkrtz(b.z, b.w);
  return r.v;
}

// ---- prepass: K16F (sigma-permuted A-frag layout) + V16T2 (PV A-frag) ----
__global__ __launch_bounds__(256)
void prepass(const float* __restrict__ K, const float* __restrict__ V,
             _Float16* __restrict__ K16F, _Float16* __restrict__ V16T2) {
  __shared__ float tile[32][128];
  const int tid  = threadIdx.x;
  const int tb   = blockIdx.x;     // 32-row k-tile, 0..63
  const int head = blockIdx.y;
  const size_t hb = (size_t)head * S * D;
  const float* Kt = K + hb + (size_t)tb * 32 * D;
  const float* Vt = V + hb + (size_t)tb * 32 * D;

#pragma unroll
  for (int it = 0; it < 4; ++it) {
    int idx = it * 256 + tid;
    int row = idx >> 5, c = idx & 31;
    *(float4*)&tile[row][c * 4] = *(const float4*)(Kt + (size_t)row * D + c * 4);
  }
  __syncthreads();
#pragma unroll
  for (int it = 0; it < 2; ++it) {
    int s = it * 256 + tid;
    int r = s & 31, g = s >> 5;
    int ds = g >> 1, hh = g & 1;
    int sr = (r & 19) | ((r & 4) << 1) | ((r & 8) >> 1);   // swap bits 2,3
    const float* src = &tile[sr][ds * 16 + 8 * hh];
    f16x8 o;
#pragma unroll
    for (int i = 0; i < 8; ++i) o[i] = (_Float16)src[i];
    *(f16x8*)(K16F + ((size_t)(head * 64 + tb) * 16 + g) * 256 + r * 8) = o;
  }
  __syncthreads();
#pragma unroll
  for (int it = 0; it < 4; ++it) {
    int idx = it * 256 + tid;
    int row = idx >> 5, c = idx & 31;
    *(float4*)&tile[row][c * 4] = *(const float4*)(Vt + (size_t)row * D + c * 4);
  }
  __syncthreads();
#pragma unroll
  for (int it = 0; it < 2; ++it) {
    int s = it * 256 + tid;
    int dd = s & 31, g = s >> 5;
    int hh = g & 1, dt = (g >> 1) & 3, kl = g >> 3;
    f16x8 o;
#pragma unroll
    for (int i = 0; i < 8; ++i) o[i] = (_Float16)tile[kl * 16 + 8 * hh + i][dt * 32 + dd];
    *(f16x8*)(V16T2 + (((size_t)(head * 128 + tb * 2 + kl) * 4 + dt) * 2 + hh) * 256 + dd * 8) = o;
  }
}

__global__ __launch_bounds__(512, 2)
void entmax_attn(const float* __restrict__ Q, const _Float16* __restrict__ K16F,
                 const _Float16* __restrict__ V16T2, float* __restrict__ O) {
  __shared__ __align__(16) char zbuf[131072];   // 32q x 4096B z rows; alias oreg
  __shared__ float taubuf[32];

  const int tid  = threadIdx.x;
  const int lane = tid & 63;
  const int wid  = tid >> 6;
  const int l31  = lane & 31;
  const int h    = lane >> 5;

  const int bi   = blockIdx.x;
  const int head = (bi & 7) * 2 + ((bi >> 3) >> 6);
  const int qb   = ((bi >> 3) & 63) * 32;

  const size_t hb = (size_t)head * S * D;
  const float* Qh = Q + hb;
  float* Oh = O + hb;

  const _Float16* kfp = K16F + ((size_t)(head * 64 + wid * 8)) * 4096 + lane * 8;
  const _Float16* vfp = V16T2 + ((size_t)(head * 128 + wid * 16)) * 2048 + lane * 8;

  const float hs = 0.04419417382415922f;  // 0.5 / sqrt(128)
  const v2h zero2 = {(_Float16)0.f, (_Float16)0.f};
  const v2h one2  = {(_Float16)1.f, (_Float16)1.f};

  // ---- Q fragments (hs folded): B[d][q], q=l31, d = ds*16 + 8h + i ----
  f16x8 qf[8];
  {
    const float* qr = Qh + (size_t)(qb + l31) * D + 8 * h;
#pragma unroll
    for (int ds = 0; ds < 8; ++ds) {
      float4 a = *(const float4*)(qr + ds * 16);
      float4 b = *(const float4*)(qr + ds * 16 + 4);
      a.x *= hs; a.y *= hs; a.z *= hs; a.w *= hs;
      b.x *= hs; b.y *= hs; b.z *= hs; b.w *= hs;
      qf[ds] = cvt8(a, b);
    }
  }

  // ---- Phase A: QK^T, ds-outer => 8 independent MFMAs per step ----
  f32x16 acc[8];
#pragma unroll
  for (int t = 0; t < 8; ++t)
#pragma unroll
    for (int e = 0; e < 16; ++e) acc[t][e] = 0.f;

  {
    f16x8 kA[8], kB[8];
#pragma unroll
    for (int t = 0; t < 8; ++t) kA[t] = *(const f16x8*)(kfp + t * 4096);
#pragma unroll
    for (int t = 0; t < 8; ++t) kB[t] = *(const f16x8*)(kfp + t * 4096 + 512);
#pragma unroll
    for (int dd = 0; dd < 4; ++dd) {
#pragma unroll
      for (int t = 0; t < 8; ++t) {
        acc[t] = __builtin_amdgcn_mfma_f32_32x32x16_f16(kA[t], qf[2 * dd], acc[t], 0, 0, 0);
        if (dd < 3) kA[t] = *(const f16x8*)(kfp + t * 4096 + (2 * dd + 2) * 512);
      }
#pragma unroll
      for (int t = 0; t < 8; ++t) {
        acc[t] = __builtin_amdgcn_mfma_f32_32x32x16_f16(kB[t], qf[2 * dd + 1], acc[t], 0, 0, 0);
        if (dd < 3) kB[t] = *(const f16x8*)(kfp + t * 4096 + (2 * dd + 3) * 512);
      }
    }
  }

  // ---- z = acc (f16, no max-sub; entmax is shift-invariant) ----
  Z z;
#pragma unroll
  for (int t = 0; t < 8; ++t)
#pragma unroll
    for (int j2 = 0; j2 < 8; ++j2) {
      PK pk;
      pk.a = __builtin_amdgcn_cvt_pkrtz(acc[t][2 * j2], acc[t][2 * j2 + 1]);
      z.v2[t * 8 + j2] = pk.b;
    }

  // ---- vr0+vr1 prefetch (32 VGPR; complete under Newton) ----
  f16x8 vr0[4], vr1[4];
#pragma unroll
  for (int dt = 0; dt < 4; ++dt) vr0[dt] = *(const f16x8*)(vfp + dt * 512);
#pragma unroll
  for (int dt = 0; dt < 4; ++dt) vr1[dt] = *(const f16x8*)(vfp + 1 * 2048 + dt * 512);

  // ---- Phase R: z -> zbuf; combined swizzle b ^ ((((b>>8)^q)&7)<<4) ----
  {
#pragma unroll
    for (int kt = 0; kt < 16; ++kt) {
      const int bb = wid * 512 + kt * 32 + 16 * h;
      const int by = l31 * 4096 + (bb ^ (((((bb >> 8)) ^ l31) & 7) << 4));
      *(f16x8*)(zbuf + by) = z.f8[kt];
    }
  }
  __syncthreads();   // barrier 1

  // ---- Phase B: wave-local row max + 6 Newton iters (4-way split) ----
  {
    const int r = lane >> 4, c = lane & 15;
    const int q = wid * 4 + r;
    const int swq = ((c ^ q) & 7) << 4;
    Z zr;
#pragma unroll
    for (int j2 = 0; j2 < 16; ++j2)
      zr.f8[j2] = *(const f16x8*)(zbuf + q * 4096 + c * 256 + ((j2 * 16) ^ swq));

    v2h mv = zr.v2[0];
#pragma unroll
    for (int j2 = 1; j2 < 64; ++j2) mv = __builtin_elementwise_max(mv, zr.v2[j2]);
    float mx = fmaxf((float)mv[0], (float)mv[1]);
#pragma unroll
    for (int off = 8; off >= 1; off >>= 1) mx = fmaxf(mx, __shfl_xor(mx, off));

    float tau = mx - 1.f;
#pragma unroll
    for (int it = 0; it < 6; ++it) {
      const _Float16 th = (_Float16)tau;
      const v2h tt = {th, th};
      float f0 = 0.f, f1 = 0.f, f2 = 0.f, f3 = 0.f;
      float g0 = 0.f, g1 = 0.f, g2 = 0.f, g3 = 0.f;
#pragma unroll
      for (int j2 = 0; j2 < 64; j2 += 4) {
        v2h d0 = __builtin_elementwise_max(zr.v2[j2 + 0] - tt, zero2);
        v2h d1 = __builtin_elementwise_max(zr.v2[j2 + 1] - tt, zero2);
        v2h d2 = __builtin_elementwise_max(zr.v2[j2 + 2] - tt, zero2);
        v2h d3 = __builtin_elementwise_max(zr.v2[j2 + 3] - tt, zero2);
#if __has_builtin(__builtin_amdgcn_fdot2)
        f0 = __builtin_amdgcn_fdot2(d0, d0, f0, false);
        g0 = __builtin_amdgcn_fdot2(d0, one2, g0, false);
        f1 = __builtin_amdgcn_fdot2(d1, d1, f1, false);
        g1 = __builtin_amdgcn_fdot2(d1, one2, g1, false);
        f2 = __builtin_amdgcn_fdot2(d2, d2, f2, false);
        g2 = __builtin_amdgcn_fdot2(d2, one2, g2, false);
        f3 = __builtin_amdgcn_fdot2(d3, d3, f3, false);
        g3 = __builtin_amdgcn_fdot2(d3, one2, g3, false);
#else
        float e0 = (float)d0[0], e1 = (float)d0[1];
        f0 = fmaf(e0, e0, fmaf(e1, e1, f0)); g0 += e0 + e1;
        e0 = (float)d1[0]; e1 = (float)d1[1];
        f1 = fmaf(e0, e0, fmaf(e1, e1, f1)); g1 += e0 + e1;
        e0 = (float)d2[0]; e1 = (float)d2[1];
        f2 = fmaf(e0, e0, fmaf(e1, e1, f2)); g2 += e0 + e1;
        e0 = (float)d3[0]; e1 = (float)d3[1];
        f3 = fmaf(e0, e0, fmaf(e1, e1, f3)); g3 += e0 + e1;
#endif
      }
      float f = (f0 + f1) + (f2 + f3);
      float g = (g0 + g1) + (g2 + g3);
#pragma unroll
      for (int off = 8; off >= 1; off >>= 1) {
        f += __shfl_xor(f, off);
        g += __shfl_xor(g, off);
      }
      tau += (f - 1.f) / (2.f * fmaxf(g, 1e-20f));
    }
    if (c == 0) taubuf[q] = tau;
  }
  __syncthreads();   // barrier 2 (zbuf reads done -> oreg alias safe)

  // ---- vr2/vr3 prefetch (in flight during Phase C VALU) ----
  f16x8 vr2[4], vr3[4];
#pragma unroll
  for (int dt = 0; dt < 4; ++dt) vr2[dt] = *(const f16x8*)(vfp + 2 * 2048 + dt * 512);
#pragma unroll
  for (int dt = 0; dt < 4; ++dt) vr3[dt] = *(const f16x8*)(vfp + 3 * 2048 + dt * 512);

  // ---- Phase C: p = (z - tau)^2 in place (sigma-layout = PV B-frags) ----
  {
    const _Float16 th = (_Float16)taubuf[l31];
    const v2h tt = {th, th};
#pragma unroll
    for (int j2 = 0; j2 < 64; ++j2) {
      v2h d = __builtin_elementwise_max(z.v2[j2] - tt, zero2);
      z.v2[j2] = d * d;
    }
  }

  // ---- Phase D: O^T partial = V^T P; static depth-4 ring, split oacc ----
  f32x16 oA[4], oB[4];
#pragma unroll
  for (int dt = 0; dt < 4; ++dt)
#pragma unroll
    for (int e = 0; e < 16; ++e) { oA[dt][e] = 0.f; oB[dt][e] = 0.f; }

#pragma unroll
  for (int kq = 0; kq < 4; ++kq) {
#pragma unroll
    for (int dt = 0; dt < 4; ++dt) {
      oA[dt] = __builtin_amdgcn_mfma_f32_32x32x16_f16(vr0[dt], z.f8[4 * kq + 0], oA[dt], 0, 0, 0);
      if (kq < 3) vr0[dt] = *(const f16x8*)(vfp + (4 * kq + 4) * 2048 + dt * 512);
    }
#pragma unroll
    for (int dt = 0; dt < 4; ++dt) {
      oB[dt] = __builtin_amdgcn_mfma_f32_32x32x16_f16(vr1[dt], z.f8[4 * kq + 1], oB[dt], 0, 0, 0);
      if (kq < 3) vr1[dt] = *(const f16x8*)(vfp + (4 * kq + 5) * 2048 + dt * 512);
    }
#pragma unroll
    for (int dt = 0; dt < 4; ++dt) {
      oA[dt] = __builtin_amdgcn_mfma_f32_32x32x16_f16(vr2[dt], z.f8[4 * kq + 2], oA[dt], 0, 0, 0);
      if (kq < 3) vr2[dt] = *(const f16x8*)(vfp + (4 * kq + 6) * 2048 + dt * 512);
    }
#pragma unroll
    for (int dt = 0; dt < 4; ++dt) {
      oB[dt] = __builtin_amdgcn_mfma_f32_32x32x16_f16(vr3[dt], z.f8[4 * kq + 3], oB[dt], 0, 0, 0);
      if (kq < 3) vr3[dt] = *(const f16x8*)(vfp + (4 * kq + 7) * 2048 + dt * 512);
    }
  }

  // ---- Phase E: 8-region partial write (alias zbuf) + coop sum ----
  {
    char* b = zbuf + wid * 16384;
#pragma unroll
    for (int dt = 0; dt < 4; ++dt)
#pragma unroll
      for (int eq = 0; eq < 4; ++eq) {
        int d0 = dt * 32 + 8 * eq + 4 * h;
        int by = l31 * 512 + ((d0 * 4) ^ ((l31 & 7) << 4));
        f32x4 v = {oA[dt][eq * 4 + 0] + oB[dt][eq * 4 + 0],
                   oA[dt][eq * 4 + 1] + oB[dt][eq * 4 + 1],
                   oA[dt][eq * 4 + 2] + oB[dt][eq * 4 + 2],
                   oA[dt][eq * 4 + 3] + oB[dt][eq * 4 + 3]};
        *(f32x4*)(b + by) = v;
      }
  }
  __syncthreads();   // barrier 3
  {
    int q = tid >> 4, dq = tid & 15;
    int by0 = q * 512 + ((dq * 32) ^ ((q & 7) << 4));
    int by1 = q * 512 + ((dq * 32 + 16) ^ ((q & 7) << 4));
    f32x4 s0 = {0.f, 0.f, 0.f, 0.f}, s1 = {0.f, 0.f, 0.f, 0.f};
#pragma unroll
    for (int r = 0; r < 8; ++r) {
      const char* b = zbuf + r * 16384;
      f32x4 v0 = *(const f32x4*)(b + by0);
      f32x4 v1 = *(const f32x4*)(b + by1);
#pragma unroll
      for (int cc = 0; cc < 4; ++cc) { s0[cc] += v0[cc]; s1[cc] += v1[cc]; }
    }
    float* op = Oh + (size_t)(qb + q) * D + dq * 8;
    *(f32x4*)op = s0;
    *(f32x4*)(op + 4) = s1;
  }
}

extern "C" void kernel_launch(void* const* d_in, const int* in_sizes, int n_in,
                              void* d_out, int out_size, void* d_ws, size_t ws_size,
                              hipStream_t stream) {
  const float* q = (const float*)d_in[0];
  const float* k = (const float*)d_in[1];
  const float* v = (const float*)d_in[2];
  float* out = (float*)d_out;

  const size_t nelem = (size_t)NH * S * D;
  _Float16* k16f  = (_Float16*)d_ws;
  _Float16* v16t2 = k16f + nelem;

  prepass<<<dim3(S / 32, NH), dim3(256), 0, stream>>>(k, v, k16f, v16t2);
  entmax_attn<<<dim3(1024), dim3(512), 0, stream>>>(q, k16f, v16t2, out);
}